// Round 1
// baseline (65.873 us; speedup 1.0000x reference)
//
#include <hip/hip_runtime.h>

#define NB 16
#define NN 256
#define NH 128
#define NE 16

constexpr long long EF_ELEMS = (long long)NB * NN * NN * NE; // 16777216

// -------------------- prep: fold dist-MLP second layer into uW1 --------------------
// M[k][c]  = sum_e dW2[k][e] * uW1[256+e][c]        (16x32)
// c2[c]    = ub1[c] + sum_e db2[e] * uW1[256+e][c]  (32)
__global__ __launch_bounds__(512) void k_prep(
    const float* __restrict__ dW2, const float* __restrict__ db2,
    const float* __restrict__ uW1, const float* __restrict__ ub1,
    float* __restrict__ M, float* __restrict__ c2)
{
    const int tid = threadIdx.x;          // 512 threads
    const int k = tid >> 5, c = tid & 31;
    float s = 0.f;
#pragma unroll
    for (int e = 0; e < 16; ++e)
        s = fmaf(dW2[k * 16 + e], uW1[(256 + e) * 32 + c], s);
    M[k * 32 + c] = s;
    if (tid < 32) {
        float s2 = ub1[tid];
#pragma unroll
        for (int e = 0; e < 16; ++e)
            s2 = fmaf(db2[e], uW1[(256 + e) * 32 + tid], s2);
        c2[tid] = s2;
    }
}

// -------------------- proj: Pi = node @ uW1[:128], Pj = node @ uW1[128:256] --------
__global__ __launch_bounds__(64) void k_proj(
    const float* __restrict__ node, const float* __restrict__ uW1,
    float* __restrict__ Pi, float* __restrict__ Pj)
{
    const int row = blockIdx.x;           // b*N + n  (4096 rows)
    const int tid = threadIdx.x;          // 64 threads
    __shared__ float nrow[128];
    nrow[tid]      = node[(size_t)row * 128 + tid];
    nrow[tid + 64] = node[(size_t)row * 128 + 64 + tid];
    __syncthreads();
    const int c = tid & 31;
    const int half = tid >> 5;            // 0 -> Pi, 1 -> Pj
    const float* w = uW1 + half * 128 * 32 + c;
    float s = 0.f;
#pragma unroll 8
    for (int k = 0; k < 128; ++k)
        s = fmaf(nrow[k], w[k * 32], s);
    (half ? Pj : Pi)[(size_t)row * 32 + c] = s;
}

// -------------------- edge: per-(b,i) block, thread j handles one edge -------------
__global__ __launch_bounds__(256) void k_edge(
    const float* __restrict__ dist, const int* __restrict__ visited,
    const float* __restrict__ dW1, const float* __restrict__ db1,
    const float* __restrict__ ln_g, const float* __restrict__ ln_b,
    const float* __restrict__ uW2, const float* __restrict__ ub2,
    const float* __restrict__ M, const float* __restrict__ c2,
    const float* __restrict__ Pi, const float* __restrict__ Pj,
    float* __restrict__ ef_out, float* __restrict__ pooled)
{
    const int row = blockIdx.x;           // b*N + i
    const int b = row >> 8;
    const int j = threadIdx.x;

    const float d = dist[(size_t)row * NN + j];
    float t[16];
#pragma unroll
    for (int k = 0; k < 16; ++k)
        t[k] = fmaxf(fmaf(d, dW1[k], db1[k]), 0.f);

    float pre[32];
    {
        const float4* pj4 = reinterpret_cast<const float4*>(Pj + ((size_t)(b * NN + j)) * 32);
#pragma unroll
        for (int q = 0; q < 8; ++q) {
            float4 v = pj4[q];
            pre[q * 4 + 0] = v.x; pre[q * 4 + 1] = v.y;
            pre[q * 4 + 2] = v.z; pre[q * 4 + 3] = v.w;
        }
    }
#pragma unroll
    for (int c = 0; c < 32; ++c)
        pre[c] += Pi[(size_t)row * 32 + c] + c2[c];   // uniform -> s_load

#pragma unroll
    for (int k = 0; k < 16; ++k) {
        const float tk = t[k];
#pragma unroll
        for (int c = 0; c < 32; ++c)
            pre[c] = fmaf(tk, M[k * 32 + c], pre[c]); // uniform -> s_load
    }

    // LayerNorm over 32 channels
    float mu = 0.f;
#pragma unroll
    for (int c = 0; c < 32; ++c) mu += pre[c];
    mu *= (1.f / 32.f);
    float var = 0.f;
#pragma unroll
    for (int c = 0; c < 32; ++c) { const float dv = pre[c] - mu; var = fmaf(dv, dv, var); }
    var *= (1.f / 32.f);
    const float rstd = rsqrtf(var + 1e-5f);
    float hc[32];
#pragma unroll
    for (int c = 0; c < 32; ++c)
        hc[c] = fmaxf(fmaf((pre[c] - mu) * rstd, ln_g[c], ln_b[c]), 0.f);

    float ef[16];
#pragma unroll
    for (int e = 0; e < 16; ++e) ef[e] = ub2[e];
#pragma unroll
    for (int c = 0; c < 32; ++c) {
        const float h = hc[c];
#pragma unroll
        for (int e = 0; e < 16; ++e)
            ef[e] = fmaf(h, uW2[c * 16 + e], ef[e]);  // uniform -> s_load
    }

    const float scale = visited[row] ? 0.5f : 1.0f;
#pragma unroll
    for (int e = 0; e < 16; ++e) ef[e] *= scale;

    // write edge_features
    float4* op = reinterpret_cast<float4*>(ef_out + ((size_t)row * NN + j) * 16);
    op[0] = make_float4(ef[0], ef[1], ef[2], ef[3]);
    op[1] = make_float4(ef[4], ef[5], ef[6], ef[7]);
    op[2] = make_float4(ef[8], ef[9], ef[10], ef[11]);
    op[3] = make_float4(ef[12], ef[13], ef[14], ef[15]);

    // block-level mean over j -> pooled[row][16]
#pragma unroll
    for (int e = 0; e < 16; ++e) {
        float v = ef[e];
        v += __shfl_down(v, 32);
        v += __shfl_down(v, 16);
        v += __shfl_down(v, 8);
        v += __shfl_down(v, 4);
        v += __shfl_down(v, 2);
        v += __shfl_down(v, 1);
        ef[e] = v;
    }
    __shared__ float part[4][16];
    const int wave = threadIdx.x >> 6;
    const int lane = threadIdx.x & 63;
    if (lane == 0) {
#pragma unroll
        for (int e = 0; e < 16; ++e) part[wave][e] = ef[e];
    }
    __syncthreads();
    if (threadIdx.x < 16) {
        const float s = part[0][threadIdx.x] + part[1][threadIdx.x]
                      + part[2][threadIdx.x] + part[3][threadIdx.x];
        pooled[(size_t)row * 16 + threadIdx.x] = s * (1.f / 256.f);
    }
}

// -------------------- node MLP: edge_messages = relu(pooled@nW1+nb1)@nW2+nb2 -------
__global__ __launch_bounds__(128) void k_node(
    const float* __restrict__ pooled,
    const float* __restrict__ nW1, const float* __restrict__ nb1,
    const float* __restrict__ nW2, const float* __restrict__ nb2,
    float* __restrict__ msg_out)
{
    const int row = blockIdx.x;           // b*N + n
    const int tid = threadIdx.x;          // 128 threads
    __shared__ float hid[64];
    __shared__ float prow[16];
    if (tid < 16) prow[tid] = pooled[(size_t)row * 16 + tid];
    __syncthreads();
    if (tid < 64) {
        float s = nb1[tid];
#pragma unroll
        for (int e = 0; e < 16; ++e)
            s = fmaf(prow[e], nW1[e * 64 + tid], s);
        hid[tid] = fmaxf(s, 0.f);
    }
    __syncthreads();
    float s = nb2[tid];
#pragma unroll 8
    for (int q = 0; q < 64; ++q)
        s = fmaf(hid[q], nW2[q * 128 + tid], s);
    msg_out[(size_t)row * 128 + tid] = s;
}

extern "C" void kernel_launch(void* const* d_in, const int* in_sizes, int n_in,
                              void* d_out, int out_size, void* d_ws, size_t ws_size,
                              hipStream_t stream)
{
    const float* node    = (const float*)d_in[0];
    const float* dist    = (const float*)d_in[1];
    const int*   visited = (const int*)  d_in[2];
    const float* dW1     = (const float*)d_in[3];
    const float* db1     = (const float*)d_in[4];
    const float* dW2     = (const float*)d_in[5];
    const float* db2     = (const float*)d_in[6];
    const float* uW1     = (const float*)d_in[7];
    const float* ub1     = (const float*)d_in[8];
    const float* ln_g    = (const float*)d_in[9];
    const float* ln_b    = (const float*)d_in[10];
    const float* uW2     = (const float*)d_in[11];
    const float* ub2     = (const float*)d_in[12];
    const float* nW1     = (const float*)d_in[13];
    const float* nb1     = (const float*)d_in[14];
    const float* nW2     = (const float*)d_in[15];
    const float* nb2     = (const float*)d_in[16];

    float* ws     = (float*)d_ws;
    float* M      = ws;                    // 512
    float* c2     = ws + 512;              // 32
    float* Pi     = ws + 544;              // 4096*32
    float* Pj     = Pi + 4096 * 32;        // 4096*32
    float* pooled = Pj + 4096 * 32;        // 4096*16

    float* out = (float*)d_out;
    float* msg = out + EF_ELEMS;

    hipLaunchKernelGGL(k_prep, dim3(1), dim3(512), 0, stream, dW2, db2, uW1, ub1, M, c2);
    hipLaunchKernelGGL(k_proj, dim3(NB * NN), dim3(64), 0, stream, node, uW1, Pi, Pj);
    hipLaunchKernelGGL(k_edge, dim3(NB * NN), dim3(256), 0, stream,
                       dist, visited, dW1, db1, ln_g, ln_b, uW2, ub2, M, c2, Pi, Pj, out, pooled);
    hipLaunchKernelGGL(k_node, dim3(NB * NN), dim3(128), 0, stream, pooled, nW1, nb1, nW2, nb2, msg);
}